// Round 11
// baseline (2917.390 us; speedup 1.0000x reference)
//
#include <hip/hip_runtime.h>
#include <hip/hip_bf16.h>

// GIN 3-layer + mean-pool + MLP head for MI355X (gfx950).
//
// Round-10: revert r9 tiling (failed: no cross-block phase coherence).
// Keep r8 facts: gather pinned at ~12.5G past-L2 transactions/s; epilogue
// VALU hidden. Attack non-gather time:
//  - DROP bucket_sort: layers are push-bucket kernels (block = 128-node
//    bucket) consuming `packed` unordered into padded LDS accs via
//    ds_add_f32 (LDS-scope atomics only; +1 pad spreads banks).
//  - Transform-first L1: y1 = x@W1 dense (folds f32->bf16 cvt), gather
//    64B rows instead of 128B ((x+Ax)W = xW + A(xW)).
//  - L2 (32-in MLP epi) / L3 (64-in MLP epi) stay input-space.

typedef float f4 __attribute__((ext_vector_type(4)));

#define NCHUNK 512
#define MAXK 1024   // K = ceil(N/128); N=100000 -> 782

__device__ __forceinline__ float elu_f(float x) {
  return x > 0.0f ? x : expm1f(x);
}

__device__ __forceinline__ float rl(float v, int q) {
  return __int_as_float(__builtin_amdgcn_readlane(__float_as_int(v), q));
}

__device__ __forceinline__ unsigned short f2bf(float f) {
  unsigned int u = __float_as_uint(f);
  u = (u + 0x7FFFu + ((u >> 16) & 1u)) >> 16;  // RNE
  return (unsigned short)u;
}

// ---------------- dense y1 = x @ W1 (f32 in, bf16 out, no bias) ----------------

__global__ __launch_bounds__(256) void gemm1_kernel(
    const float* __restrict__ x, const float* __restrict__ W,
    unsigned short* __restrict__ y, int N) {
  const int lane = threadIdx.x & 63;
  const int wid = blockIdx.x * 4 + (threadIdx.x >> 6);
  const int nw = gridDim.x * 4;
  const int fo = lane & 31;
  float wcol[64];
#pragma unroll
  for (int k = 0; k < 64; ++k) wcol[k] = W[k * 32 + fo];
  for (int n = wid; n < N; n += nw) {
    float a[4] = {0.f, 0.f, 0.f, 0.f};
    if (lane < 16) {
      const f4 v = *reinterpret_cast<const f4*>(x + (long long)n * 64 + lane * 4);
      a[0] = v.x; a[1] = v.y; a[2] = v.z; a[3] = v.w;
    }
    float o0 = 0.f, o1 = 0.f;
#pragma unroll
    for (int k = 0; k < 64; k += 2) {
      o0 = fmaf(rl(a[k & 3], k >> 2), wcol[k], o0);
      o1 = fmaf(rl(a[(k + 1) & 3], (k + 1) >> 2), wcol[k + 1], o1);
    }
    if (lane < 32) y[(long long)n * 32 + lane] = f2bf(o0 + o1);
  }
}

// ---------------- atomic-free bucket partition (hist/scan/scatter) ----------------

__global__ __launch_bounds__(256) void bucket_hist_kernel(
    const int* __restrict__ dst, int* __restrict__ bhist, int E, int K, int chunk) {
  __shared__ int h[MAXK];
  for (int k = threadIdx.x; k < K; k += 256) h[k] = 0;
  __syncthreads();
  const int base = blockIdx.x * chunk;
  const int end = min(E, base + chunk);
  for (int e = base + threadIdx.x; e < end; e += 256)
    atomicAdd(&h[dst[e] >> 7], 1);
  __syncthreads();
  int* row = bhist + (long long)blockIdx.x * K;
  for (int k = threadIdx.x; k < K; k += 256) row[k] = h[k];
}

__global__ __launch_bounds__(NCHUNK) void chunk_scan_kernel(
    const int* __restrict__ bhist, int* __restrict__ cursors,
    int* __restrict__ btot, int K) {
  const int k = blockIdx.x;
  const int t = threadIdx.x;
  const int lane = t & 63;
  const int wv = t >> 6;  // 8 waves
  const int own = bhist[(long long)t * K + k];
  int v = own;
#pragma unroll
  for (int off = 1; off < 64; off <<= 1) {
    int u = __shfl_up(v, off, 64);
    if (lane >= off) v += u;
  }
  __shared__ int wsum[8];
  __shared__ int wpre[8];
  if (lane == 63) wsum[wv] = v;
  __syncthreads();
  if (t == 0) {
    int p = 0;
#pragma unroll
    for (int w = 0; w < 8; ++w) { wpre[w] = p; p += wsum[w]; }
  }
  __syncthreads();
  v += wpre[wv];
  cursors[(long long)t * K + k] = v - own;  // exclusive
  if (t == NCHUNK - 1) btot[k] = v;
}

__global__ __launch_bounds__(1024) void bucket_scan_kernel(
    const int* __restrict__ btot, int* __restrict__ bstart, int K) {
  __shared__ int s[1024];
  const int t = threadIdx.x;
  const int own = (t < K) ? btot[t] : 0;
  s[t] = own;
  __syncthreads();
#pragma unroll
  for (int off = 1; off < 1024; off <<= 1) {
    int v = (t >= off) ? s[t - off] : 0;
    __syncthreads();
    s[t] += v;
    __syncthreads();
  }
  if (t < K) bstart[t] = s[t] - own;
  if (t == K - 1) bstart[K] = s[t];
}

__global__ __launch_bounds__(256) void bucket_scatter_kernel(
    const int* __restrict__ src, const int* __restrict__ dst,
    const int* __restrict__ cursors, const int* __restrict__ bstart,
    int* __restrict__ packed, int E, int K, int chunk) {
  __shared__ int cur[MAXK];
  const int c = blockIdx.x;
  for (int k = threadIdx.x; k < K; k += 256)
    cur[k] = cursors[(long long)c * K + k] + bstart[k];
  __syncthreads();
  const int base = c * chunk;
  const int end = min(E, base + chunk);
  for (int e = base + threadIdx.x; e < end; e += 256) {
    const int d = dst[e];
    const int k = d >> 7;
    const int p = atomicAdd(&cur[k], 1);
    packed[p] = ((d & 127) << 18) | src[e];
  }
}

// ---------------- push-bucket aggregate + epilogue ----------------
// Block (512 thr) = bucket of 128 nodes; consume packed[e0..e1) unordered,
// accumulate bf16 rows into padded LDS accs via ds_add_f32; add self row;
// epilogue: EPI 0 = elementwise elu(acc + b) (FO=FPW=32),
//           EPI 1 = MLP 32->64, EPI 2 = MLP 64->64 (wcol in VGPR).
template <int FPW, int EPI>
__global__ __launch_bounds__(512) void agg_kernel(
    const unsigned short* __restrict__ y, const int* __restrict__ packed,
    const int* __restrict__ bstart, const float* __restrict__ W,
    const float* __restrict__ bias, unsigned short* __restrict__ out, int N) {
  constexpr int STR = FPW + 1;     // pad -> bank = (dl + 8*li + j) % 32
  __shared__ float accs[128][STR];
  const int t = threadIdx.x;
  const int lane = t & 63;
  const int wv = t >> 6;           // 0..7
  const int kblk = blockIdx.x;
  const int n0 = kblk << 7;
  const int e0 = bstart[kblk];
  const int e1 = bstart[kblk + 1];

  float wcol[(EPI == 2) ? 64 : ((EPI == 1) ? 32 : 1)];
  if constexpr (EPI == 1) {
#pragma unroll
    for (int k = 0; k < 32; ++k) wcol[k] = W[k * 64 + lane];
  } else if constexpr (EPI == 2) {
#pragma unroll
    for (int k = 0; k < 64; ++k) wcol[k] = W[k * 64 + lane];
  }

  for (int i = t; i < 128 * STR; i += 512) ((float*)accs)[i] = 0.0f;
  __syncthreads();

  constexpr int LPG = FPW / 8;     // lanes per group (8B..): 8 (64f) / 4 (32f)
  constexpr int GPW = 64 / LPG;    // edges per wave-iter: 8 / 16
  constexpr int EPB = GPW * 8;     // edges per block-iter
  const int grp = lane / LPG;
  const int li = lane % LPG;       // feats li*8 .. li*8+7

  int eb = e0 + wv * GPW + grp;
  // unroll-2: two rows in flight before the LDS adds
  for (; eb + EPB < e1; eb += 2 * EPB) {
    const int w0 = packed[eb];
    const int w1 = packed[eb + EPB];
    const int s0 = w0 & 0x3FFFF;
    const int s1 = w1 & 0x3FFFF;
    const uint4 r0 = *reinterpret_cast<const uint4*>(y + (long long)s0 * FPW + li * 8);
    const uint4 r1 = *reinterpret_cast<const uint4*>(y + (long long)s1 * FPW + li * 8);
    float* a0 = &accs[w0 >> 18][li * 8];
    atomicAdd(a0 + 0, __uint_as_float(r0.x << 16));
    atomicAdd(a0 + 1, __uint_as_float(r0.x & 0xffff0000u));
    atomicAdd(a0 + 2, __uint_as_float(r0.y << 16));
    atomicAdd(a0 + 3, __uint_as_float(r0.y & 0xffff0000u));
    atomicAdd(a0 + 4, __uint_as_float(r0.z << 16));
    atomicAdd(a0 + 5, __uint_as_float(r0.z & 0xffff0000u));
    atomicAdd(a0 + 6, __uint_as_float(r0.w << 16));
    atomicAdd(a0 + 7, __uint_as_float(r0.w & 0xffff0000u));
    float* a1 = &accs[w1 >> 18][li * 8];
    atomicAdd(a1 + 0, __uint_as_float(r1.x << 16));
    atomicAdd(a1 + 1, __uint_as_float(r1.x & 0xffff0000u));
    atomicAdd(a1 + 2, __uint_as_float(r1.y << 16));
    atomicAdd(a1 + 3, __uint_as_float(r1.y & 0xffff0000u));
    atomicAdd(a1 + 4, __uint_as_float(r1.z << 16));
    atomicAdd(a1 + 5, __uint_as_float(r1.z & 0xffff0000u));
    atomicAdd(a1 + 6, __uint_as_float(r1.w << 16));
    atomicAdd(a1 + 7, __uint_as_float(r1.w & 0xffff0000u));
  }
  for (; eb < e1; eb += EPB) {
    const int w = packed[eb];
    const int s = w & 0x3FFFF;
    const uint4 r = *reinterpret_cast<const uint4*>(y + (long long)s * FPW + li * 8);
    float* ap = &accs[w >> 18][li * 8];
    atomicAdd(ap + 0, __uint_as_float(r.x << 16));
    atomicAdd(ap + 1, __uint_as_float(r.x & 0xffff0000u));
    atomicAdd(ap + 2, __uint_as_float(r.y << 16));
    atomicAdd(ap + 3, __uint_as_float(r.y & 0xffff0000u));
    atomicAdd(ap + 4, __uint_as_float(r.z << 16));
    atomicAdd(ap + 5, __uint_as_float(r.z & 0xffff0000u));
    atomicAdd(ap + 6, __uint_as_float(r.w << 16));
    atomicAdd(ap + 7, __uint_as_float(r.w & 0xffff0000u));
  }
  __syncthreads();

  // add self row (exclusive per thread, no atomics)
  constexpr int TPN = FPW / 8;
  for (int i = t; i < 128 * TPN; i += 512) {
    const int node = i / TPN;
    const int seg = i % TPN;
    const int n = n0 + node;
    if (n < N) {
      const uint4 r = *reinterpret_cast<const uint4*>(y + (long long)n * FPW + seg * 8);
      float* ap = &accs[node][seg * 8];
      ap[0] += __uint_as_float(r.x << 16);
      ap[1] += __uint_as_float(r.x & 0xffff0000u);
      ap[2] += __uint_as_float(r.y << 16);
      ap[3] += __uint_as_float(r.y & 0xffff0000u);
      ap[4] += __uint_as_float(r.z << 16);
      ap[5] += __uint_as_float(r.z & 0xffff0000u);
      ap[6] += __uint_as_float(r.w << 16);
      ap[7] += __uint_as_float(r.w & 0xffff0000u);
    }
  }
  __syncthreads();

  if constexpr (EPI == 0) {
    const int f = t & 31;
    const float bb = bias[f];
    for (int node = t >> 5; node < 128; node += 16) {
      const int n = n0 + node;
      if (n < N) out[(long long)n * 32 + f] = f2bf(elu_f(accs[node][f] + bb));
    }
  } else {
    constexpr int KK = (EPI == 1) ? 32 : 64;
    const float bb = bias[lane];
    for (int node = wv; node < 128; node += 8) {
      const int n = n0 + node;
      if (n < N) {
        float o0 = bb, o1 = 0.f;
#pragma unroll
        for (int k = 0; k < KK; k += 2) {
          o0 = fmaf(accs[node][k], wcol[k], o0);
          o1 = fmaf(accs[node][k + 1], wcol[k + 1], o1);
        }
        out[(long long)n * 64 + lane] = f2bf(elu_f(o0 + o1));
      }
    }
  }
}

// ---------------- pooling + head ----------------

__global__ void pool_kernel(const unsigned short* __restrict__ h,
                            const int* __restrict__ batch,
                            float* __restrict__ sums,
                            float* __restrict__ cnts,
                            int N) {
  const int groupsPerBlock = blockDim.x >> 6;
  const int grp = blockIdx.x * groupsPerBlock + (threadIdx.x >> 6);
  const int ngrp = gridDim.x * groupsPerBlock;
  const int f = threadIdx.x & 63;
  const int chunk = (N + ngrp - 1) / ngrp;
  const int n0 = grp * chunk;
  const int n1 = min(N, n0 + chunk);
  if (n0 >= n1) return;
  int g = batch[n0];
  float acc = 0.0f;
  float cnt = 0.0f;
  for (int n = n0; n < n1; ++n) {
    const int bg = batch[n];
    if (bg != g) {
      atomicAdd(&sums[(long long)g * 64 + f], acc);
      if (f == 0) atomicAdd(&cnts[g], cnt);
      acc = 0.0f;
      cnt = 0.0f;
      g = bg;
    }
    acc += __uint_as_float((unsigned int)h[(long long)n * 64 + f] << 16);
    cnt += 1.0f;
  }
  atomicAdd(&sums[(long long)g * 64 + f], acc);
  if (f == 0) atomicAdd(&cnts[g], cnt);
}

__global__ void head_kernel(const float* __restrict__ sums,
                            const float* __restrict__ cnts,
                            const float* __restrict__ Wf1, const float* __restrict__ bf1,
                            const float* __restrict__ Wf2, const float* __restrict__ bf2,
                            const float* __restrict__ Wf3, const float* __restrict__ bf3,
                            float* __restrict__ out, int G) {
  __shared__ float s0[64];
  __shared__ float s1[64];
  __shared__ float s2[32];
  const int g = blockIdx.x;
  const int t = threadIdx.x;
  const float c = fmaxf(cnts[g], 1.0f);
  s0[t] = sums[(long long)g * 64 + t] / c;
  __syncthreads();
  float acc = bf1[t];
#pragma unroll
  for (int k = 0; k < 64; ++k) acc += s0[k] * Wf1[k * 64 + t];
  s1[t] = elu_f(acc);
  __syncthreads();
  if (t < 32) {
    float a2 = bf2[t];
#pragma unroll
    for (int k = 0; k < 64; ++k) a2 += s1[k] * Wf2[k * 32 + t];
    s2[t] = elu_f(a2) * Wf3[t];
  }
  __syncthreads();
  if (t == 0) {
    float r = bf3[0];
#pragma unroll
    for (int k = 0; k < 32; ++k) r += s2[k];
    out[g] = r;
  }
}

extern "C" void kernel_launch(void* const* d_in, const int* in_sizes, int n_in,
                              void* d_out, int out_size, void* d_ws, size_t ws_size,
                              hipStream_t stream) {
  const float* x   = (const float*)d_in[0];
  const int* ei    = (const int*)d_in[1];
  const int* batch = (const int*)d_in[2];
  const float* W1  = (const float*)d_in[4];
  const float* b1  = (const float*)d_in[5];
  const float* W2  = (const float*)d_in[6];
  const float* b2  = (const float*)d_in[7];
  const float* W3  = (const float*)d_in[8];
  const float* b3  = (const float*)d_in[9];
  const float* Wf1 = (const float*)d_in[10];
  const float* bf1 = (const float*)d_in[11];
  const float* Wf2 = (const float*)d_in[12];
  const float* bf2 = (const float*)d_in[13];
  const float* Wf3 = (const float*)d_in[14];
  const float* bf3 = (const float*)d_in[15];

  const int N = in_sizes[0] / 64;
  const int E = in_sizes[1] / 2;
  const int G = out_size;
  const int* src = ei;
  const int* dst = ei + E;
  const int K = (N + 127) >> 7;
  const int chunk = (E + NCHUNK - 1) / NCHUNK;

  char* ws = (char*)d_ws;
  size_t off = 0;
  auto alloc = [&](size_t bytes) -> void* {
    void* p = ws + off;
    off = (off + bytes + 255) & ~(size_t)255;
    return p;
  };
  int* bhist   = (int*)alloc((size_t)NCHUNK * K * 4);
  int* cursors = (int*)alloc((size_t)NCHUNK * K * 4);
  int* btot    = (int*)alloc((size_t)K * 4);
  int* bstart  = (int*)alloc((size_t)(K + 1) * 4);
  int* packed  = (int*)alloc((size_t)E * 4);
  unsigned short* y1 = (unsigned short*)alloc((size_t)N * 32 * 2);
  unsigned short* hA = (unsigned short*)alloc((size_t)N * 64 * 2);
  unsigned short* hB = (unsigned short*)alloc((size_t)N * 64 * 2);
  float* sums  = (float*)alloc((size_t)G * 65 * 4);  // sums[G*64] + cnts[G]
  float* cnts  = sums + (size_t)G * 64;
  float* out   = (float*)d_out;

  // ---- y1 = x @ W1 (folds f32->bf16) ----
  gemm1_kernel<<<1024, 256, 0, stream>>>(x, W1, y1, N);

  // ---- bucket partition (atomic-free; LDS atomics only) ----
  bucket_hist_kernel<<<NCHUNK, 256, 0, stream>>>(dst, bhist, E, K, chunk);
  chunk_scan_kernel<<<K, NCHUNK, 0, stream>>>(bhist, cursors, btot, K);
  bucket_scan_kernel<<<1, 1024, 0, stream>>>(btot, bstart, K);
  bucket_scatter_kernel<<<NCHUNK, 256, 0, stream>>>(src, dst, cursors, bstart,
                                                    packed, E, K, chunk);

  // ---- layers: push-bucket aggregate ----
  agg_kernel<32, 0><<<K, 512, 0, stream>>>(y1, packed, bstart, nullptr, b1, hA, N);
  agg_kernel<32, 1><<<K, 512, 0, stream>>>(hA, packed, bstart, W2, b2, hB, N);
  agg_kernel<64, 2><<<K, 512, 0, stream>>>(hB, packed, bstart, W3, b3, hA, N);

  // ---- mean pool + head ----
  hipMemsetAsync(sums, 0, (size_t)G * 65 * 4, stream);
  pool_kernel<<<512, 256, 0, stream>>>(hA, batch, sums, cnts, N);
  head_kernel<<<G, 64, 0, stream>>>(sums, cnts, Wf1, bf1, Wf2, bf2, Wf3, bf3, out, G);
}

// Round 12
// 461.682 us; speedup vs baseline: 6.3190x; 6.3190x over previous
//
#include <hip/hip_runtime.h>
#include <hip/hip_bf16.h>

// GIN 3-layer + mean-pool + MLP head for MI355X (gfx950).
//
// Round-12: revert to round-8 structure (best measured: per-node wave gather,
// register accumulation, atomic-free counting-sort CSR). Two structural
// attempts to beat it (r9 src-tiling, r10 push-bucket LDS atomics) both lost
// by losing memory-level parallelism. Single graft from r11 (verified
// correct there): transform-first L1 -- y1 = x@W1 dense (folds f32->bf16),
// then L1 = elu(y1 + A*y1 + b1): 64B-row gather + elementwise epilogue.

typedef float f4 __attribute__((ext_vector_type(4)));

#define NCHUNK 512
#define MAXK 1024  // K = ceil(N/128); N=100000 -> 782

__device__ __forceinline__ float elu_f(float x) {
  return x > 0.0f ? x : expm1f(x);
}

__device__ __forceinline__ float rl(float v, int q) {
  return __int_as_float(__builtin_amdgcn_readlane(__float_as_int(v), q));
}

__device__ __forceinline__ unsigned short f2bf(float f) {
  unsigned int u = __float_as_uint(f);
  u = (u + 0x7FFFu + ((u >> 16) & 1u)) >> 16;  // RNE
  return (unsigned short)u;
}

// unpack uint4 = 8 bf16 and accumulate into a[0..7]
__device__ __forceinline__ void acc_add8(float* a, const uint4 w) {
  a[0] += __uint_as_float(w.x << 16);
  a[1] += __uint_as_float(w.x & 0xffff0000u);
  a[2] += __uint_as_float(w.y << 16);
  a[3] += __uint_as_float(w.y & 0xffff0000u);
  a[4] += __uint_as_float(w.z << 16);
  a[5] += __uint_as_float(w.z & 0xffff0000u);
  a[6] += __uint_as_float(w.w << 16);
  a[7] += __uint_as_float(w.w & 0xffff0000u);
}

// ---------------- dense y1 = x @ W1 (f32 in, bf16 out, NO bias) ----------------

__global__ __launch_bounds__(256) void gemm1_kernel(
    const float* __restrict__ x, const float* __restrict__ W,
    unsigned short* __restrict__ y, int N) {
  const int lane = threadIdx.x & 63;
  const int wid = blockIdx.x * 4 + (threadIdx.x >> 6);
  const int nw = gridDim.x * 4;
  const int fo = lane & 31;
  float wcol[64];
#pragma unroll
  for (int k = 0; k < 64; ++k) wcol[k] = W[k * 32 + fo];
  for (int n = wid; n < N; n += nw) {
    float a[4] = {0.f, 0.f, 0.f, 0.f};
    if (lane < 16) {
      const f4 v = *reinterpret_cast<const f4*>(x + (long long)n * 64 + lane * 4);
      a[0] = v.x; a[1] = v.y; a[2] = v.z; a[3] = v.w;
    }
    float o0 = 0.f, o1 = 0.f;
#pragma unroll
    for (int k = 0; k < 64; k += 2) {
      o0 = fmaf(rl(a[k & 3], k >> 2), wcol[k], o0);
      o1 = fmaf(rl(a[(k + 1) & 3], (k + 1) >> 2), wcol[k + 1], o1);
    }
    if (lane < 32) y[(long long)n * 32 + lane] = f2bf(o0 + o1);
  }
}

// ---------------- atomic-free CSR build (round-8) ----------------

__global__ __launch_bounds__(256) void bucket_hist_kernel(
    const int* __restrict__ dst, int* __restrict__ bhist, int E, int K, int chunk) {
  __shared__ int h[MAXK];
  for (int k = threadIdx.x; k < K; k += 256) h[k] = 0;
  __syncthreads();
  const int base = blockIdx.x * chunk;
  const int end = min(E, base + chunk);
  for (int e = base + threadIdx.x; e < end; e += 256)
    atomicAdd(&h[dst[e] >> 7], 1);
  __syncthreads();
  int* row = bhist + (long long)blockIdx.x * K;
  for (int k = threadIdx.x; k < K; k += 256) row[k] = h[k];
}

__global__ __launch_bounds__(NCHUNK) void chunk_scan_kernel(
    const int* __restrict__ bhist, int* __restrict__ cursors,
    int* __restrict__ btot, int K) {
  const int k = blockIdx.x;
  const int t = threadIdx.x;
  const int lane = t & 63;
  const int wv = t >> 6;  // 8 waves
  const int own = bhist[(long long)t * K + k];
  int v = own;
#pragma unroll
  for (int off = 1; off < 64; off <<= 1) {
    int u = __shfl_up(v, off, 64);
    if (lane >= off) v += u;
  }
  __shared__ int wsum[8];
  __shared__ int wpre[8];
  if (lane == 63) wsum[wv] = v;
  __syncthreads();
  if (t == 0) {
    int p = 0;
#pragma unroll
    for (int w = 0; w < 8; ++w) { wpre[w] = p; p += wsum[w]; }
  }
  __syncthreads();
  v += wpre[wv];
  cursors[(long long)t * K + k] = v - own;  // exclusive
  if (t == NCHUNK - 1) btot[k] = v;
}

__global__ __launch_bounds__(1024) void bucket_scan_kernel(
    const int* __restrict__ btot, int* __restrict__ bstart, int K) {
  __shared__ int s[1024];
  const int t = threadIdx.x;
  const int own = (t < K) ? btot[t] : 0;
  s[t] = own;
  __syncthreads();
#pragma unroll
  for (int off = 1; off < 1024; off <<= 1) {
    int v = (t >= off) ? s[t - off] : 0;
    __syncthreads();
    s[t] += v;
    __syncthreads();
  }
  if (t < K) bstart[t] = s[t] - own;
  if (t == K - 1) bstart[K] = s[t];
}

__global__ __launch_bounds__(256) void bucket_scatter_kernel(
    const int* __restrict__ src, const int* __restrict__ dst,
    const int* __restrict__ cursors, const int* __restrict__ bstart,
    int* __restrict__ packed, int E, int K, int chunk) {
  __shared__ int cur[MAXK];
  const int c = blockIdx.x;
  for (int k = threadIdx.x; k < K; k += 256)
    cur[k] = cursors[(long long)c * K + k] + bstart[k];
  __syncthreads();
  const int base = c * chunk;
  const int end = min(E, base + chunk);
  for (int e = base + threadIdx.x; e < end; e += 256) {
    const int d = dst[e];
    const int k = d >> 7;
    const int p = atomicAdd(&cur[k], 1);
    packed[p] = ((d & 127) << 18) | src[e];
  }
}

__global__ __launch_bounds__(256) void bucket_sort_kernel(
    const int* __restrict__ packed, const int* __restrict__ bstart,
    int* __restrict__ rowptr, int* __restrict__ eidx, int N, int E, int K) {
  __shared__ int hcnt[128];
  __shared__ int ccur[128];
  __shared__ int wtot;
  const int k = blockIdx.x;
  const int t = threadIdx.x;
  const int lane = t & 63;
  const int n0 = k << 7;
  const int e0 = bstart[k];
  const int e1 = bstart[k + 1];
  if (t < 128) hcnt[t] = 0;
  __syncthreads();
  for (int e = e0 + t; e < e1; e += 256)
    atomicAdd(&hcnt[packed[e] >> 18], 1);
  __syncthreads();
  int v = 0, own = 0;
  if (t < 128) {
    own = hcnt[t];
    v = own;
#pragma unroll
    for (int off = 1; off < 64; off <<= 1) {
      int u = __shfl_up(v, off, 64);
      if (lane >= off) v += u;
    }
  }
  if (t == 63) wtot = v;
  __syncthreads();
  if (t >= 64 && t < 128) v += wtot;
  if (t < 128) {
    const int excl = v - own;
    ccur[t] = excl;
    if (n0 + t < N) rowptr[n0 + t] = e0 + excl;
  }
  if (k == 0 && t == 0) rowptr[N] = E;
  __syncthreads();
  for (int e = e0 + t; e < e1; e += 256) {
    const int w = packed[e];
    const int dl = w >> 18;
    const int p = atomicAdd(&ccur[dl], 1);
    eidx[e0 + p] = w & 0x3FFFF;
  }
}

// ---------------- fused bf16 gather layers (round-8 structure) ----------------

// L1: FI=32 gather over y1 + ELEMENTWISE epilogue elu(acc + b1) -> 32-feat out.
// 16 groups of 4 lanes; row = 64B; 16 edges/instr, unroll 2, dual banks.
__global__ __launch_bounds__(256) void gin_layer32_elem_kernel(
    const unsigned short* __restrict__ h, const int* __restrict__ rowptr,
    const int* __restrict__ eidx, const float* __restrict__ b,
    unsigned short* __restrict__ out, int N) {
  const int lane = threadIdx.x & 63;
  const int grp = lane >> 2;       // edge slot 0..15
  const int li = lane & 3;         // features li*8 .. li*8+7
  const int wid = blockIdx.x * (blockDim.x >> 6) + (threadIdx.x >> 6);
  const int nw = gridDim.x * (blockDim.x >> 6);
  float bb[8];
#pragma unroll
  for (int j = 0; j < 8; ++j) bb[j] = b[li * 8 + j];

  for (int n = wid; n < N; n += nw) {
    const int r0 = rowptr[n];
    const int cnt = rowptr[n + 1] - r0;
    float a[8] = {0.f, 0.f, 0.f, 0.f, 0.f, 0.f, 0.f, 0.f};
    float a2[8] = {0.f, 0.f, 0.f, 0.f, 0.f, 0.f, 0.f, 0.f};
    int i = grp;
    for (; i + 16 < cnt; i += 32) {
      const int s0 = eidx[r0 + i];
      const int s1 = eidx[r0 + i + 16];
      const uint4 w0 = *reinterpret_cast<const uint4*>(h + (long long)s0 * 32 + li * 8);
      const uint4 w1 = *reinterpret_cast<const uint4*>(h + (long long)s1 * 32 + li * 8);
      acc_add8(a, w0);
      acc_add8(a2, w1);
    }
    if (i < cnt) {
      const int s = eidx[r0 + i];
      acc_add8(a, *reinterpret_cast<const uint4*>(h + (long long)s * 32 + li * 8));
    }
#pragma unroll
    for (int j = 0; j < 8; ++j) {
      a[j] += a2[j];
      a[j] += __shfl_xor(a[j], 4, 64);
      a[j] += __shfl_xor(a[j], 8, 64);
      a[j] += __shfl_xor(a[j], 16, 64);
      a[j] += __shfl_xor(a[j], 32, 64);
    }
    acc_add8(a, *reinterpret_cast<const uint4*>(h + (long long)n * 32 + li * 8));
    // elementwise epilogue; lanes of grp 0 (0..3) write the 64B row
    if (grp == 0) {
      uint4 o;
      o.x = (unsigned int)f2bf(elu_f(a[0] + bb[0])) |
            ((unsigned int)f2bf(elu_f(a[1] + bb[1])) << 16);
      o.y = (unsigned int)f2bf(elu_f(a[2] + bb[2])) |
            ((unsigned int)f2bf(elu_f(a[3] + bb[3])) << 16);
      o.z = (unsigned int)f2bf(elu_f(a[4] + bb[4])) |
            ((unsigned int)f2bf(elu_f(a[5] + bb[5])) << 16);
      o.w = (unsigned int)f2bf(elu_f(a[6] + bb[6])) |
            ((unsigned int)f2bf(elu_f(a[7] + bb[7])) << 16);
      *reinterpret_cast<uint4*>(out + (long long)n * 32 + li * 8) = o;
    }
  }
}

// L2: FI=32, FO=64 (round-8): 16 groups of 4 lanes; readlane MLP epilogue.
__global__ __launch_bounds__(256) void gin_layer32_kernel(
    const unsigned short* __restrict__ h, const int* __restrict__ rowptr,
    const int* __restrict__ eidx, const float* __restrict__ W,
    const float* __restrict__ b, unsigned short* __restrict__ out, int N) {
  const int lane = threadIdx.x & 63;
  const int grp = lane >> 2;
  const int li = lane & 3;
  const int wid = blockIdx.x * (blockDim.x >> 6) + (threadIdx.x >> 6);
  const int nw = gridDim.x * (blockDim.x >> 6);
  float wcol[32];
#pragma unroll
  for (int k = 0; k < 32; ++k) wcol[k] = W[k * 64 + lane];
  const float bias = b[lane];

  for (int n = wid; n < N; n += nw) {
    const int r0 = rowptr[n];
    const int cnt = rowptr[n + 1] - r0;
    float a[8] = {0.f, 0.f, 0.f, 0.f, 0.f, 0.f, 0.f, 0.f};
    float a2[8] = {0.f, 0.f, 0.f, 0.f, 0.f, 0.f, 0.f, 0.f};
    int i = grp;
    for (; i + 16 < cnt; i += 32) {
      const int s0 = eidx[r0 + i];
      const int s1 = eidx[r0 + i + 16];
      const uint4 w0 = *reinterpret_cast<const uint4*>(h + (long long)s0 * 32 + li * 8);
      const uint4 w1 = *reinterpret_cast<const uint4*>(h + (long long)s1 * 32 + li * 8);
      acc_add8(a, w0);
      acc_add8(a2, w1);
    }
    if (i < cnt) {
      const int s = eidx[r0 + i];
      acc_add8(a, *reinterpret_cast<const uint4*>(h + (long long)s * 32 + li * 8));
    }
#pragma unroll
    for (int j = 0; j < 8; ++j) {
      a[j] += a2[j];
      a[j] += __shfl_xor(a[j], 4, 64);
      a[j] += __shfl_xor(a[j], 8, 64);
      a[j] += __shfl_xor(a[j], 16, 64);
      a[j] += __shfl_xor(a[j], 32, 64);
    }
    acc_add8(a, *reinterpret_cast<const uint4*>(h + (long long)n * 32 + li * 8));
    float o0 = bias, o1 = 0.0f;
#pragma unroll
    for (int k = 0; k < 32; k += 2) {
      o0 = fmaf(rl(a[k & 7], k >> 3), wcol[k], o0);
      o1 = fmaf(rl(a[(k + 1) & 7], (k + 1) >> 3), wcol[k + 1], o1);
    }
    out[(long long)n * 64 + lane] = f2bf(elu_f(o0 + o1));
  }
}

// L3: FI=64, FO=64 (round-8): 8 groups of 8 lanes; 128B rows; readlane MLP.
__global__ __launch_bounds__(256) void gin_layer64_kernel(
    const unsigned short* __restrict__ h, const int* __restrict__ rowptr,
    const int* __restrict__ eidx, const float* __restrict__ W,
    const float* __restrict__ b, unsigned short* __restrict__ out, int N) {
  const int lane = threadIdx.x & 63;
  const int grp = lane >> 3;
  const int li = lane & 7;
  const int wid = blockIdx.x * (blockDim.x >> 6) + (threadIdx.x >> 6);
  const int nw = gridDim.x * (blockDim.x >> 6);
  float wcol[64];
#pragma unroll
  for (int k = 0; k < 64; ++k) wcol[k] = W[k * 64 + lane];
  const float bias = b[lane];

  for (int n = wid; n < N; n += nw) {
    const int r0 = rowptr[n];
    const int cnt = rowptr[n + 1] - r0;
    float a[8] = {0.f, 0.f, 0.f, 0.f, 0.f, 0.f, 0.f, 0.f};
    float a2[8] = {0.f, 0.f, 0.f, 0.f, 0.f, 0.f, 0.f, 0.f};
    int i = grp;
    for (; i + 8 < cnt; i += 16) {
      const int s0 = eidx[r0 + i];
      const int s1 = eidx[r0 + i + 8];
      const uint4 w0 = *reinterpret_cast<const uint4*>(h + (long long)s0 * 64 + li * 8);
      const uint4 w1 = *reinterpret_cast<const uint4*>(h + (long long)s1 * 64 + li * 8);
      acc_add8(a, w0);
      acc_add8(a2, w1);
    }
    if (i < cnt) {
      const int s = eidx[r0 + i];
      acc_add8(a, *reinterpret_cast<const uint4*>(h + (long long)s * 64 + li * 8));
    }
#pragma unroll
    for (int j = 0; j < 8; ++j) {
      a[j] += a2[j];
      a[j] += __shfl_xor(a[j], 8, 64);
      a[j] += __shfl_xor(a[j], 16, 64);
      a[j] += __shfl_xor(a[j], 32, 64);
    }
    acc_add8(a, *reinterpret_cast<const uint4*>(h + (long long)n * 64 + li * 8));
    float o0 = bias, o1 = 0.0f;
#pragma unroll
    for (int k = 0; k < 64; k += 2) {
      o0 = fmaf(rl(a[k & 7], k >> 3), wcol[k], o0);
      o1 = fmaf(rl(a[(k + 1) & 7], (k + 1) >> 3), wcol[k + 1], o1);
    }
    out[(long long)n * 64 + lane] = f2bf(elu_f(o0 + o1));
  }
}

// ---------------- pooling + head ----------------

__global__ void pool_kernel(const unsigned short* __restrict__ h,
                            const int* __restrict__ batch,
                            float* __restrict__ sums,
                            float* __restrict__ cnts,
                            int N) {
  const int groupsPerBlock = blockDim.x >> 6;
  const int grp = blockIdx.x * groupsPerBlock + (threadIdx.x >> 6);
  const int ngrp = gridDim.x * groupsPerBlock;
  const int f = threadIdx.x & 63;
  const int chunk = (N + ngrp - 1) / ngrp;
  const int n0 = grp * chunk;
  const int n1 = min(N, n0 + chunk);
  if (n0 >= n1) return;
  int g = batch[n0];
  float acc = 0.0f;
  float cnt = 0.0f;
  for (int n = n0; n < n1; ++n) {
    const int bg = batch[n];
    if (bg != g) {
      atomicAdd(&sums[(long long)g * 64 + f], acc);
      if (f == 0) atomicAdd(&cnts[g], cnt);
      acc = 0.0f;
      cnt = 0.0f;
      g = bg;
    }
    acc += __uint_as_float((unsigned int)h[(long long)n * 64 + f] << 16);
    cnt += 1.0f;
  }
  atomicAdd(&sums[(long long)g * 64 + f], acc);
  if (f == 0) atomicAdd(&cnts[g], cnt);
}

__global__ void head_kernel(const float* __restrict__ sums,
                            const float* __restrict__ cnts,
                            const float* __restrict__ Wf1, const float* __restrict__ bf1,
                            const float* __restrict__ Wf2, const float* __restrict__ bf2,
                            const float* __restrict__ Wf3, const float* __restrict__ bf3,
                            float* __restrict__ out, int G) {
  __shared__ float s0[64];
  __shared__ float s1[64];
  __shared__ float s2[32];
  const int g = blockIdx.x;
  const int t = threadIdx.x;
  const float c = fmaxf(cnts[g], 1.0f);
  s0[t] = sums[(long long)g * 64 + t] / c;
  __syncthreads();
  float acc = bf1[t];
#pragma unroll
  for (int k = 0; k < 64; ++k) acc += s0[k] * Wf1[k * 64 + t];
  s1[t] = elu_f(acc);
  __syncthreads();
  if (t < 32) {
    float a2 = bf2[t];
#pragma unroll
    for (int k = 0; k < 64; ++k) a2 += s1[k] * Wf2[k * 32 + t];
    s2[t] = elu_f(a2) * Wf3[t];
  }
  __syncthreads();
  if (t == 0) {
    float r = bf3[0];
#pragma unroll
    for (int k = 0; k < 32; ++k) r += s2[k];
    out[g] = r;
  }
}

extern "C" void kernel_launch(void* const* d_in, const int* in_sizes, int n_in,
                              void* d_out, int out_size, void* d_ws, size_t ws_size,
                              hipStream_t stream) {
  const float* x   = (const float*)d_in[0];
  const int* ei    = (const int*)d_in[1];
  const int* batch = (const int*)d_in[2];
  const float* W1  = (const float*)d_in[4];
  const float* b1  = (const float*)d_in[5];
  const float* W2  = (const float*)d_in[6];
  const float* b2  = (const float*)d_in[7];
  const float* W3  = (const float*)d_in[8];
  const float* b3  = (const float*)d_in[9];
  const float* Wf1 = (const float*)d_in[10];
  const float* bf1 = (const float*)d_in[11];
  const float* Wf2 = (const float*)d_in[12];
  const float* bf2 = (const float*)d_in[13];
  const float* Wf3 = (const float*)d_in[14];
  const float* bf3 = (const float*)d_in[15];

  const int N = in_sizes[0] / 64;
  const int E = in_sizes[1] / 2;
  const int G = out_size;
  const int* src = ei;
  const int* dst = ei + E;
  const int K = (N + 127) >> 7;
  const int chunk = (E + NCHUNK - 1) / NCHUNK;

  char* ws = (char*)d_ws;
  size_t off = 0;
  auto alloc = [&](size_t bytes) -> void* {
    void* p = ws + off;
    off = (off + bytes + 255) & ~(size_t)255;
    return p;
  };
  int* bhist   = (int*)alloc((size_t)NCHUNK * K * 4);
  int* cursors = (int*)alloc((size_t)NCHUNK * K * 4);
  int* btot    = (int*)alloc((size_t)K * 4);
  int* bstart  = (int*)alloc((size_t)(K + 1) * 4);
  int* rowptr  = (int*)alloc((size_t)(N + 1) * 4);
  int* eidx    = (int*)alloc((size_t)E * 4);
  int* packed  = (int*)alloc((size_t)E * 4);
  unsigned short* y1 = (unsigned short*)alloc((size_t)N * 32 * 2);
  unsigned short* hA = (unsigned short*)alloc((size_t)N * 64 * 2);
  unsigned short* hB = (unsigned short*)alloc((size_t)N * 64 * 2);
  float* sums  = (float*)alloc((size_t)G * 65 * 4);  // sums[G*64] + cnts[G]
  float* cnts  = sums + (size_t)G * 64;
  float* out   = (float*)d_out;

  // ---- y1 = x @ W1 (folds f32->bf16; bias deferred to L1 epilogue) ----
  gemm1_kernel<<<1024, 256, 0, stream>>>(x, W1, y1, N);

  // ---- atomic-free CSR build ----
  bucket_hist_kernel<<<NCHUNK, 256, 0, stream>>>(dst, bhist, E, K, chunk);
  chunk_scan_kernel<<<K, NCHUNK, 0, stream>>>(bhist, cursors, btot, K);
  bucket_scan_kernel<<<1, 1024, 0, stream>>>(btot, bstart, K);
  bucket_scatter_kernel<<<NCHUNK, 256, 0, stream>>>(src, dst, cursors, bstart,
                                                    packed, E, K, chunk);
  bucket_sort_kernel<<<K, 256, 0, stream>>>(packed, bstart, rowptr, eidx, N, E, K);

  // ---- layers ----
  gin_layer32_elem_kernel<<<2048, 256, 0, stream>>>(y1, rowptr, eidx, b1, hA, N);
  gin_layer32_kernel<<<2048, 256, 0, stream>>>(hA, rowptr, eidx, W2, b2, hB, N);
  gin_layer64_kernel<<<2048, 256, 0, stream>>>(hB, rowptr, eidx, W3, b3, hA, N);

  // ---- mean pool + head ----
  hipMemsetAsync(sums, 0, (size_t)G * 65 * 4, stream);
  pool_kernel<<<512, 256, 0, stream>>>(hA, batch, sums, cnts, N);
  head_kernel<<<G, 64, 0, stream>>>(sums, cnts, Wf1, bf1, Wf2, bf2, Wf3, bf3, out, G);
}